// Round 3
// baseline (866.131 us; speedup 1.0000x reference)
//
#include <hip/hip_runtime.h>
#include <hip/hip_bf16.h>
#include <math.h>

#define B_ 8
#define S_ 1024
#define E_ 1024
#define H_ 16
#define HD_ 64
#define F_ 4096
#define M_ (B_ * S_)   // 8192

typedef float f32x4 __attribute__((ext_vector_type(4)));
typedef short short8 __attribute__((ext_vector_type(8)));

__device__ inline unsigned short f2bf(float x) {
    union { float f; unsigned int u; } v; v.f = x;
    unsigned int r = (v.u + 0x7fffu + ((v.u >> 16) & 1u)) >> 16;
    return (unsigned short)r;
}
__device__ inline float bf2f(unsigned short u) {
    union { unsigned int u; float f; } v; v.u = ((unsigned int)u) << 16;
    return v.f;
}

// inline erf, Abramowitz-Stegun 7.1.26, |err| < 1.5e-7 — NO libcall (erff() is a
// real ABI call on this toolchain: it spilled the MFMA accumulators around 64
// calls/thread in the epilogue -> 6.8 GB of scratch traffic, 1347us dispatch)
__device__ inline float erf_inline(float x) {
    float ax = __builtin_fabsf(x);
    float t = __builtin_amdgcn_rcpf(1.0f + 0.3275911f * ax);
    float y = t * (0.254829592f + t * (-0.284496736f + t * (1.421413741f +
              t * (-1.453152027f + t * 1.061405429f))));
    float e = __expf(-ax * ax);
    float r = 1.0f - y * e;
    union { float f; unsigned int u; } s, o;
    s.f = x; o.f = r;
    o.u = (o.u & 0x7fffffffu) | (s.u & 0x80000000u);
    return o.f;
}

#define AS1 __attribute__((address_space(1)))
#define AS3 __attribute__((address_space(3)))
__device__ inline void gload_lds16(const void* g, void* l) {
    __builtin_amdgcn_global_load_lds((const AS1 unsigned int*)(g),
                                     (AS3 unsigned int*)(l), 16, 0, 0);
}

// ---------------- cast x fp32 -> bf16 ----------------
__global__ __launch_bounds__(256) void cast_f32_bf16(const float* __restrict__ in,
                                                     unsigned short* __restrict__ out) {
    int i = (blockIdx.x * 256 + threadIdx.x) * 4;
    float4 v = *(const float4*)(in + i);
    ushort4 o;
    o.x = f2bf(v.x); o.y = f2bf(v.y); o.z = f2bf(v.z); o.w = f2bf(v.w);
    *(ushort4*)(out + i) = o;
}

// ---------------- mask prep: per (b,s) additive -1e30/0 and q-side 0/1 float ----------------
__global__ __launch_bounds__(256) void mask_prep(const int* __restrict__ am,
                                                 const int* __restrict__ tt,
                                                 float* __restrict__ amqf,
                                                 float* __restrict__ negadd) {
    int i = blockIdx.x * 256 + threadIdx.x;   // i in [0, B*S)
    int s = i & (S_ - 1);
    int a = am[i], t = tt[i];
    amqf[i] = (a != 0) ? 1.0f : 0.0f;
    negadd[i] = ((t == 1) || (a == 0) || (s == 0)) ? -1e30f : 0.0f;
}

// ---------------- transpose+cast weight: in[K,N] f32 -> out[N,K] bf16 ----------------
__global__ __launch_bounds__(256) void transpose_cast(const float* __restrict__ in,
                                                      unsigned short* __restrict__ out,
                                                      int K, int N) {
    __shared__ float tile[32][33];
    int n0 = blockIdx.x * 32, k0 = blockIdx.y * 32;
    int tc = threadIdx.x & 31, tr = threadIdx.x >> 5;  // tr 0..7
    for (int i = 0; i < 4; ++i) {
        int k = k0 + tr + i * 8;
        tile[tr + i * 8][tc] = in[(size_t)k * N + n0 + tc];
    }
    __syncthreads();
    for (int i = 0; i < 4; ++i) {
        int n = n0 + tr + i * 8;
        out[(size_t)n * K + k0 + tc] = f2bf(tile[tc][tr + i * 8]);
    }
}

// ---------------- GEMM: C[M,N] = A[M,K](bf16) @ Bt[N,K]^T(bf16) + bias, epilogues ----------------
// EPI 0: qkv  -> bias, scale cols<1024 by 1/8, store bf16
// EPI 1: gelu -> bias, exact gelu (inline erf), store bf16
// EPI 2: res  -> bias + res[row*N+col], store fp32
#define BM 128
#define BN 128
#define BK 32
template <int EPI>
__global__ __launch_bounds__(256) void gemm_bt(const unsigned short* __restrict__ A,
                                               const unsigned short* __restrict__ Bt,
                                               const float* __restrict__ bias,
                                               const float* __restrict__ res,
                                               unsigned short* __restrict__ Cb,
                                               float* __restrict__ Cf,
                                               int M, int N, int K) {
    __shared__ unsigned short lA[BM * BK];
    __shared__ unsigned short lB[BN * BK];
    int row0 = blockIdx.y * BM, col0 = blockIdx.x * BN;
    int t = threadIdx.x;
    int lane = t & 63, w = t >> 6;
    int wr = w >> 1, wc = w & 1;
    int qa = lane >> 4, ml = lane & 15;

    f32x4 acc[4][4] = {};
    const unsigned short* Aptr = A + (size_t)row0 * K;
    const unsigned short* Bptr = Bt + (size_t)col0 * K;

    for (int k0 = 0; k0 < K; k0 += BK) {
        __syncthreads();
        for (int i = 0; i < 2; ++i) {
            int c = t + i * 256;
            int r = c >> 2, kc = c & 3;
            gload_lds16(Aptr + (size_t)r * K + k0 + kc * 8, lA + c * 8);
            gload_lds16(Bptr + (size_t)r * K + k0 + kc * 8, lB + c * 8);
        }
        __syncthreads();
        short8 af[4], bfr[4];
        for (int i = 0; i < 4; ++i)
            af[i] = *(const short8*)&lA[(wr * 64 + i * 16 + ml) * BK + qa * 8];
        for (int j = 0; j < 4; ++j)
            bfr[j] = *(const short8*)&lB[(wc * 64 + j * 16 + ml) * BK + qa * 8];
        for (int i = 0; i < 4; ++i)
            for (int j = 0; j < 4; ++j)
                acc[i][j] = __builtin_amdgcn_mfma_f32_16x16x32_bf16(af[i], bfr[j], acc[i][j], 0, 0, 0);
    }

    for (int i = 0; i < 4; ++i) {
        for (int j = 0; j < 4; ++j) {
            int col = col0 + wc * 64 + j * 16 + ml;
            float bv = bias[col];
            for (int r = 0; r < 4; ++r) {
                int row = row0 + wr * 64 + i * 16 + qa * 4 + r;
                float cv = acc[i][j][r] + bv;
                if (EPI == 0) {
                    if (col < 1024) cv *= 0.125f;
                    Cb[(size_t)row * N + col] = f2bf(cv);
                } else if (EPI == 1) {
                    cv = 0.5f * cv * (1.0f + erf_inline(cv * 0.70710678118654752f));
                    Cb[(size_t)row * N + col] = f2bf(cv);
                } else {
                    cv += res[(size_t)row * N + col];
                    Cf[(size_t)row * N + col] = cv;
                }
            }
        }
    }
}

// ---------------- transpose v slice of qkv -> vT[b,h,d,s] ----------------
__global__ __launch_bounds__(256) void transpose_v(const unsigned short* __restrict__ qkv,
                                                   unsigned short* __restrict__ vT) {
    __shared__ unsigned short tile[64][72];
    int s0 = blockIdx.x * 64;
    int pair = blockIdx.y;
    int b = pair >> 4, h = pair & 15;
    int t = threadIdx.x;
    int r = t >> 2, c0 = (t & 3) * 16;
    const unsigned short* src = qkv + (size_t)(b * S_ + s0 + r) * 3072 + 2048 + h * 64 + c0;
    *(short8*)&tile[r][c0] = *(const short8*)src;
    *(short8*)&tile[r][c0 + 8] = *(const short8*)(src + 8);
    __syncthreads();
    int d = t >> 2, sc0 = (t & 3) * 16;
    unsigned short tmp[16];
    for (int i = 0; i < 16; ++i) tmp[i] = tile[sc0 + i][d];
    unsigned short* dst = vT + ((size_t)pair * 64 + d) * S_ + s0 + sc0;
    *(short8*)dst = *(const short8*)&tmp[0];
    *(short8*)(dst + 8) = *(const short8*)&tmp[8];
}

// ---------------- flash attention v5: swapped-QK^T in-register softmax ----------------
// wave w owns q-rows [qc*64 + w*16, +16). 8 k-chunks of 128 keys.
// QK^T computed as mfma(A=K, B=Q) -> score tile TRANSPOSED: lane (qa,ml) holds
// S[key = ks*16 + qa*4 + r][q = ml]. Row stats (max/sum over keys) are lane-local
// over 32 values + 2 cross-qa shuffles (xor16/xor32). P never touches LDS:
// exp results are packed to bf16 with v_cvt_pk_bf16_f32 (src0->lo, per T12 recipe)
// and redistributed to the PV A-fragment layout (lane needs keys qa*8..+7 of q=ml).
// v4 used v_permlane32_swap_b32 for the half exchange -> FAILED refcheck
// (absmax 0.1875: key-permutation signature; the instruction's lo/hi pairing is
// ambiguous). v5 builds the same combined registers with unambiguous shuffles:
//   A = {u.lo | v.lo} = hi ? shfl_xor(v,32) : u
//   B = {u.hi | v.hi} = hi ? v : shfl_xor(u,32)
//   pk.u[0] = odd ? xor16(B) : A      (keys qa*8+0,1)   [verified all 4 qa cases]
//   pk.u[2] = odd ? B : xor16(A)      (keys qa*8+4,5)
// alpha/l live at q=ml lanes; O accumulator has q=qa*4+r -> 4 shfl/chunk.
// K chunk staged in LDS via global_load_lds with XOR source-permute swizzle
// (unchanged): LDS slot s of row holds global chunk s^(row&7).
__global__ __launch_bounds__(256) void attn_flash(const unsigned short* __restrict__ qkv,
                                                  const unsigned short* __restrict__ vT,
                                                  const float* __restrict__ amqf,
                                                  const float* __restrict__ negadd,
                                                  unsigned short* __restrict__ ctx) {
    __shared__ unsigned short lK[128 * 64];       // swizzled [key][slot], 16 KB (no lP!)
    int qc = blockIdx.x;                          // 0..15
    int pair = blockIdx.y;
    int b = pair >> 4, h = pair & 15;
    int t = threadIdx.x, w = t >> 6, lane = t & 63;
    int qa = lane >> 4, ml = lane & 15;
    int q0 = qc * 64 + w * 16;                    // wave's first q-row

    // Q B-frags straight from global (col = q = q0+ml, k-dim = qa*8 / 32+qa*8)
    const unsigned short* qrow = qkv + (size_t)(b * S_ + q0 + ml) * 3072 + h * 64;
    short8 bq0 = *(const short8*)(qrow + qa * 8);
    short8 bq1 = *(const short8*)(qrow + 32 + qa * 8);
    float amq = amqf[b * S_ + q0 + ml];           // q-side additive (q = ml)
    const f32x4* na4 = (const f32x4*)(negadd + b * S_);

    // staging addresses (chunk c = w*256 + i*64 + lane -> row=c>>3, slot=c&7)
    const unsigned short* ksrc[4];
    unsigned short* kdst[4];
    for (int i = 0; i < 4; ++i) {
        int c = w * 256 + i * 64 + lane;
        int row = c >> 3, slot = c & 7, e8 = slot ^ (row & 7);
        ksrc[i] = qkv + (size_t)(b * S_ + row) * 3072 + 1024 + h * 64 + e8 * 8;
        kdst[i] = lK + c * 8;
    }
    int sw0 = qa ^ (ml & 7);                // slot holding dim-chunk qa of key
    int sw1 = (qa + 4) ^ (ml & 7);          // slot holding dim-chunk qa+4
    int qa4 = qa * 4;
    int gbase = lane & 48;                  // own 16-lane group base for shfl
    bool hi = lane >= 32;                   // qa >= 2
    bool odd = (qa & 1);

    float m_old = -3e38f;
    float l = 0.f;
    f32x4 O[4] = {};

    for (int kc = 0; kc < 8; ++kc) {
        int kk0 = kc * 128;
        __syncthreads();                               // lK free from previous chunk
        for (int i = 0; i < 4; ++i)
            gload_lds16(ksrc[i] + (size_t)kk0 * 3072, kdst[i]);
        __syncthreads();                               // staging complete

        // scores (transposed): 8 subtiles of 16 keys; masks folded in
        f32x4 sacc[8];
        for (int ks = 0; ks < 8; ++ks) {
            int keyoff = (ks * 16 + ml) * 64;
            short8 ak0 = *(const short8*)(lK + keyoff + sw0 * 8);
            short8 ak1 = *(const short8*)(lK + keyoff + sw1 * 8);
            f32x4 a = {};
            a = __builtin_amdgcn_mfma_f32_16x16x32_bf16(ak0, bq0, a, 0, 0, 0);
            a = __builtin_amdgcn_mfma_f32_16x16x32_bf16(ak1, bq1, a, 0, 0, 0);
            f32x4 nb = na4[(kk0 >> 2) + ks * 4 + qa];  // negadd[key], key=kk0+ks*16+qa*4+r
            for (int r = 0; r < 4; ++r) a[r] += amq + nb[r];
            sacc[ks] = a;
        }

        // running max: lane-local over 32 keys, then cross-qa
        float m = m_old;
        for (int ks = 0; ks < 8; ++ks)
            for (int r = 0; r < 4; ++r) m = fmaxf(m, sacc[ks][r]);
        m = fmaxf(m, __shfl_xor(m, 16));
        m = fmaxf(m, __shfl_xor(m, 32));
        float m_new = m;
        float alpha = __expf(m_old - m_new);
        m_old = m_new;

        // exp + pack to bf16 PV A-frags in-register (no LDS round trip)
        float s_sum = 0.f;
        short8 pfrag[4];
        for (int kst = 0; kst < 4; ++kst) {
            f32x4 e0, e1;
            for (int r = 0; r < 4; ++r) {
                e0[r] = __expf(sacc[2 * kst][r] - m_new);
                e1[r] = __expf(sacc[2 * kst + 1][r] - m_new);
                s_sum += e0[r] + e1[r];
            }
            unsigned int u0, u1, v0, v1;
            asm("v_cvt_pk_bf16_f32 %0, %1, %2" : "=v"(u0) : "v"(e0[0]), "v"(e0[1]));
            asm("v_cvt_pk_bf16_f32 %0, %1, %2" : "=v"(u1) : "v"(e0[2]), "v"(e0[3]));
            asm("v_cvt_pk_bf16_f32 %0, %1, %2" : "=v"(v0) : "v"(e1[0]), "v"(e1[1]));
            asm("v_cvt_pk_bf16_f32 %0, %1, %2" : "=v"(v1) : "v"(e1[2]), "v"(e1[3]));
            // unambiguous half-exchange: A = {u.lo|v.lo}, B = {u.hi|v.hi}
            unsigned int u0x = __shfl_xor(u0, 32), v0x = __shfl_xor(v0, 32);
            unsigned int u1x = __shfl_xor(u1, 32), v1x = __shfl_xor(v1, 32);
            unsigned int A0 = hi ? v0x : u0;
            unsigned int B0 = hi ? v0  : u0x;
            unsigned int A1 = hi ? v1x : u1;
            unsigned int B1 = hi ? v1  : u1x;
            unsigned int A0x = __shfl_xor(A0, 16), B0x = __shfl_xor(B0, 16);
            unsigned int A1x = __shfl_xor(A1, 16), B1x = __shfl_xor(B1, 16);
            union { short8 s8; unsigned int u[4]; } pk;
            pk.u[0] = odd ? B0x : A0;   // keys qa*8+0,1
            pk.u[1] = odd ? B1x : A1;   // keys qa*8+2,3
            pk.u[2] = odd ? B0  : A0x;  // keys qa*8+4,5
            pk.u[3] = odd ? B1  : A1x;  // keys qa*8+6,7
            pfrag[kst] = pk.s8;
        }

        // sum reduce + stats update (per q = ml)
        s_sum += __shfl_xor(s_sum, 16);
        s_sum += __shfl_xor(s_sum, 32);
        l = l * alpha + s_sum;

        // distribute alpha to O layout (q = qa*4+r) and rescale O
        float alf[4];
        for (int r = 0; r < 4; ++r)
            alf[r] = __shfl(alpha, gbase | (qa4 + r));
        for (int ds = 0; ds < 4; ++ds)
            for (int r = 0; r < 4; ++r)
                O[ds][r] *= alf[r];

        // PV: P[16x128] @ V[128x64] (V via vT rows, contiguous in s)
        for (int ds = 0; ds < 4; ++ds) {
            const unsigned short* vtp = vT + ((size_t)pair * 64 + ds * 16 + ml) * S_ + kk0;
            for (int kst = 0; kst < 4; ++kst) {
                short8 bp = *(const short8*)(vtp + kst * 32 + qa * 8);
                O[ds] = __builtin_amdgcn_mfma_f32_16x16x32_bf16(pfrag[kst], bp, O[ds], 0, 0, 0);
            }
        }
    }
    // epilogue: l lives at q=ml lanes; O rows are q=qa*4+r
    for (int r = 0; r < 4; ++r) {
        float lr = __shfl(l, gbase | (qa4 + r));
        float inv = 1.0f / lr;
        size_t orow = (size_t)(b * S_ + q0 + qa4 + r) * E_ + h * 64;
        for (int ds = 0; ds < 4; ++ds)
            ctx[orow + ds * 16 + ml] = f2bf(O[ds][r] * inv);
    }
}

// ---------------- row LayerNorm over E=1024 ----------------
template <int WRITE_BF16>
__global__ __launch_bounds__(256) void ln_kernel(const float* __restrict__ in,
                                                 const float* __restrict__ lw,
                                                 const float* __restrict__ lb,
                                                 float* __restrict__ outf,
                                                 unsigned short* __restrict__ outb) {
    int row = blockIdx.x;
    int t = threadIdx.x;
    const float* x = in + (size_t)row * E_;
    float4 v = ((const float4*)x)[t];
    float s = v.x + v.y + v.z + v.w;
    float sq = v.x * v.x + v.y * v.y + v.z * v.z + v.w * v.w;
    for (int o = 32; o >= 1; o >>= 1) {
        s += __shfl_xor(s, o, 64);
        sq += __shfl_xor(sq, o, 64);
    }
    __shared__ float red[8];
    if ((t & 63) == 0) { red[t >> 6] = s; red[4 + (t >> 6)] = sq; }
    __syncthreads();
    s = red[0] + red[1] + red[2] + red[3];
    sq = red[4] + red[5] + red[6] + red[7];
    float mu = s * (1.0f / E_);
    float var = sq * (1.0f / E_) - mu * mu;
    float rstd = rsqrtf(fmaxf(var, 0.0f) + 1e-12f);
    float4 wv = ((const float4*)lw)[t];
    float4 bv = ((const float4*)lb)[t];
    float4 o;
    o.x = (v.x - mu) * rstd * wv.x + bv.x;
    o.y = (v.y - mu) * rstd * wv.y + bv.y;
    o.z = (v.z - mu) * rstd * wv.z + bv.z;
    o.w = (v.w - mu) * rstd * wv.w + bv.w;
    ((float4*)(outf + (size_t)row * E_))[t] = o;
    if (WRITE_BF16) {
        ushort4 ob;
        ob.x = f2bf(o.x); ob.y = f2bf(o.y); ob.z = f2bf(o.z); ob.w = f2bf(o.w);
        ((ushort4*)(outb + (size_t)row * E_))[t] = ob;
    }
}

extern "C" void kernel_launch(void* const* d_in, const int* in_sizes, int n_in,
                              void* d_out, int out_size, void* d_ws, size_t ws_size,
                              hipStream_t stream) {
    const float* x        = (const float*)d_in[0];
    const int*   am       = (const int*)d_in[1];
    const int*   tt       = (const int*)d_in[2];
    const float* in_w     = (const float*)d_in[3];
    const float* in_b     = (const float*)d_in[4];
    const float* out_w    = (const float*)d_in[5];
    const float* out_b    = (const float*)d_in[6];
    const float* ln_w     = (const float*)d_in[7];
    const float* ln_b     = (const float*)d_in[8];
    const float* w_in     = (const float*)d_in[9];
    const float* b_in     = (const float*)d_in[10];
    const float* w_out    = (const float*)d_in[11];
    const float* b_out    = (const float*)d_in[12];
    float* out = (float*)d_out;

    const size_t MB = 1024 * 1024;
    char* ws = (char*)d_ws;
    unsigned short* xb    = (unsigned short*)(ws + 0);        // 16 MB (reused as hb)
    unsigned short* hb    = xb;
    unsigned short* wqkvT = (unsigned short*)(ws + 16 * MB);  // 6 MB
    unsigned short* woutT = (unsigned short*)(ws + 22 * MB);  // 2 MB
    unsigned short* winT  = (unsigned short*)(ws + 24 * MB);  // 8 MB
    unsigned short* wo2T  = (unsigned short*)(ws + 32 * MB);  // 8 MB
    unsigned short* qkvb  = (unsigned short*)(ws + 40 * MB);  // 48 MB
    unsigned short* vT    = (unsigned short*)(ws + 88 * MB);  // 16 MB
    unsigned short* ctx   = (unsigned short*)(ws + 104 * MB); // 16 MB
    float*          res1  = (float*)(ws + 120 * MB);          // 32 MB (reused for res2)
    float*          hbuf  = (float*)(ws + 152 * MB);          // 32 MB
    unsigned short* ffmid = (unsigned short*)(ws + 184 * MB); // 64 MB  -> total 248 MB
    // mask floats live in the ffmid region (unused until gemm3, attn is done by then)
    float*          amqf  = (float*)(ws + 184 * MB);          // 32 KB
    float*          negadd= (float*)(ws + 185 * MB);          // 32 KB

    // 1. cast x -> bf16; mask prep
    cast_f32_bf16<<<dim3(M_ * E_ / 1024), 256, 0, stream>>>(x, xb);
    mask_prep<<<dim3(M_ / 256), 256, 0, stream>>>(am, tt, amqf, negadd);
    // 2. transpose-cast weights
    transpose_cast<<<dim3(3 * E_ / 32, E_ / 32), 256, 0, stream>>>(in_w, wqkvT, E_, 3 * E_);
    transpose_cast<<<dim3(E_ / 32, E_ / 32), 256, 0, stream>>>(out_w, woutT, E_, E_);
    transpose_cast<<<dim3(F_ / 32, E_ / 32), 256, 0, stream>>>(w_in, winT, E_, F_);
    transpose_cast<<<dim3(E_ / 32, F_ / 32), 256, 0, stream>>>(w_out, wo2T, F_, E_);
    // 3. qkv = x @ in_proj_w + in_proj_b  (q scaled by 1/8)
    gemm_bt<0><<<dim3(3 * E_ / BN, M_ / BM), 256, 0, stream>>>(xb, wqkvT, in_b, nullptr,
                                                               qkvb, nullptr, M_, 3 * E_, E_);
    // 4. vT
    transpose_v<<<dim3(S_ / 64, B_ * H_), 256, 0, stream>>>(qkvb, vT);
    // 5. attention -> ctx
    attn_flash<<<dim3(S_ / 64, B_ * H_), 256, 0, stream>>>(qkvb, vT, amqf, negadd, ctx);
    // 6. attn_out + x  (fp32)
    gemm_bt<2><<<dim3(E_ / BN, M_ / BM), 256, 0, stream>>>(ctx, woutT, out_b, x,
                                                           nullptr, res1, M_, E_, E_);
    // 7. LN1 -> hbuf (f32) + hb (bf16)
    ln_kernel<1><<<dim3(M_), 256, 0, stream>>>(res1, ln_w, ln_b, hbuf, hb);
    // 8. ffmid = gelu(h @ w_in + b_in)
    gemm_bt<1><<<dim3(F_ / BN, M_ / BM), 256, 0, stream>>>(hb, winT, b_in, nullptr,
                                                           ffmid, nullptr, M_, F_, E_);
    // 9. ff + h (fp32)
    gemm_bt<2><<<dim3(E_ / BN, M_ / BM), 256, 0, stream>>>(ffmid, wo2T, b_out, hbuf,
                                                           nullptr, res1, M_, E_, F_);
    // 10. LN2 -> out
    ln_kernel<0><<<dim3(M_), 256, 0, stream>>>(res1, ln_w, ln_b, out, nullptr);
}

// Round 7
// 679.286 us; speedup vs baseline: 1.2751x; 1.2751x over previous
//
#include <hip/hip_runtime.h>
#include <hip/hip_bf16.h>
#include <math.h>

#define B_ 8
#define S_ 1024
#define E_ 1024
#define H_ 16
#define HD_ 64
#define F_ 4096
#define M_ (B_ * S_)   // 8192

typedef float f32x4 __attribute__((ext_vector_type(4)));
typedef short short8 __attribute__((ext_vector_type(8)));

__device__ inline unsigned short f2bf(float x) {
    union { float f; unsigned int u; } v; v.f = x;
    unsigned int r = (v.u + 0x7fffu + ((v.u >> 16) & 1u)) >> 16;
    return (unsigned short)r;
}
__device__ inline float bf2f(unsigned short u) {
    union { unsigned int u; float f; } v; v.u = ((unsigned int)u) << 16;
    return v.f;
}

// inline erf, Abramowitz-Stegun 7.1.26, |err| < 1.5e-7 — NO libcall (erff() is a
// real ABI call on this toolchain: it spilled the MFMA accumulators around 64
// calls/thread in the epilogue -> 6.8 GB of scratch traffic, 1347us dispatch)
__device__ inline float erf_inline(float x) {
    float ax = __builtin_fabsf(x);
    float t = __builtin_amdgcn_rcpf(1.0f + 0.3275911f * ax);
    float y = t * (0.254829592f + t * (-0.284496736f + t * (1.421413741f +
              t * (-1.453152027f + t * 1.061405429f))));
    float e = __expf(-ax * ax);
    float r = 1.0f - y * e;
    union { float f; unsigned int u; } s, o;
    s.f = x; o.f = r;
    o.u = (o.u & 0x7fffffffu) | (s.u & 0x80000000u);
    return o.f;
}

#define AS1 __attribute__((address_space(1)))
#define AS3 __attribute__((address_space(3)))
__device__ inline void gload_lds16(const void* g, void* l) {
    __builtin_amdgcn_global_load_lds((const AS1 unsigned int*)(g),
                                     (AS3 unsigned int*)(l), 16, 0, 0);
}

// ---------------- cast x fp32 -> bf16 ----------------
__global__ __launch_bounds__(256) void cast_f32_bf16(const float* __restrict__ in,
                                                     unsigned short* __restrict__ out) {
    int i = (blockIdx.x * 256 + threadIdx.x) * 4;
    float4 v = *(const float4*)(in + i);
    ushort4 o;
    o.x = f2bf(v.x); o.y = f2bf(v.y); o.z = f2bf(v.z); o.w = f2bf(v.w);
    *(ushort4*)(out + i) = o;
}

// ---------------- mask prep: per (b,s) additive -1e30/0 and q-side 0/1 float ----------------
__global__ __launch_bounds__(256) void mask_prep(const int* __restrict__ am,
                                                 const int* __restrict__ tt,
                                                 float* __restrict__ amqf,
                                                 float* __restrict__ negadd) {
    int i = blockIdx.x * 256 + threadIdx.x;   // i in [0, B*S)
    int s = i & (S_ - 1);
    int a = am[i], t = tt[i];
    amqf[i] = (a != 0) ? 1.0f : 0.0f;
    negadd[i] = ((t == 1) || (a == 0) || (s == 0)) ? -1e30f : 0.0f;
}

// ---------------- transpose+cast weight: in[K,N] f32 -> out[N,K] bf16 ----------------
__global__ __launch_bounds__(256) void transpose_cast(const float* __restrict__ in,
                                                      unsigned short* __restrict__ out,
                                                      int K, int N) {
    __shared__ float tile[32][33];
    int n0 = blockIdx.x * 32, k0 = blockIdx.y * 32;
    int tc = threadIdx.x & 31, tr = threadIdx.x >> 5;  // tr 0..7
    for (int i = 0; i < 4; ++i) {
        int k = k0 + tr + i * 8;
        tile[tr + i * 8][tc] = in[(size_t)k * N + n0 + tc];
    }
    __syncthreads();
    for (int i = 0; i < 4; ++i) {
        int n = n0 + tr + i * 8;
        out[(size_t)n * K + k0 + tc] = f2bf(tile[tc][tr + i * 8]);
    }
}

// ---------------- GEMM: C[M,N] = A[M,K](bf16) @ Bt[N,K]^T(bf16) + bias, epilogues ----------------
// EPI 0: qkv  -> bias, scale cols<1024 by 1/8, store bf16
// EPI 1: gelu -> bias, exact gelu (inline erf), store bf16
// EPI 2: res  -> bias + res[row*N+col], store fp32
// R6: XCD-aware bijective block swizzle (T1): all four launches have nwg%8==0
// (1536/512/2048/512), so swz = (lin&7)*(nwg/8) + lin>>3 gives each XCD a
// contiguous chunk of the linearized grid -> neighbor tiles share A/B panels in
// the same per-XCD L2. Pure index permutation, correctness-neutral.
#define BM 128
#define BN 128
#define BK 32
template <int EPI>
__global__ __launch_bounds__(256) void gemm_bt(const unsigned short* __restrict__ A,
                                               const unsigned short* __restrict__ Bt,
                                               const float* __restrict__ bias,
                                               const float* __restrict__ res,
                                               unsigned short* __restrict__ Cb,
                                               float* __restrict__ Cf,
                                               int M, int N, int K) {
    __shared__ unsigned short lA[BM * BK];
    __shared__ unsigned short lB[BN * BK];
    int gx = gridDim.x;
    int lin = blockIdx.x + blockIdx.y * gx;
    int nwg = gx * gridDim.y;                 // divisible by 8 for all launches
    int swz = (lin & 7) * (nwg >> 3) + (lin >> 3);
    int bx = swz % gx, by = swz / gx;
    int row0 = by * BM, col0 = bx * BN;
    int t = threadIdx.x;
    int lane = t & 63, w = t >> 6;
    int wr = w >> 1, wc = w & 1;
    int qa = lane >> 4, ml = lane & 15;

    f32x4 acc[4][4] = {};
    const unsigned short* Aptr = A + (size_t)row0 * K;
    const unsigned short* Bptr = Bt + (size_t)col0 * K;

    for (int k0 = 0; k0 < K; k0 += BK) {
        __syncthreads();
        for (int i = 0; i < 2; ++i) {
            int c = t + i * 256;
            int r = c >> 2, kc = c & 3;
            gload_lds16(Aptr + (size_t)r * K + k0 + kc * 8, lA + c * 8);
            gload_lds16(Bptr + (size_t)r * K + k0 + kc * 8, lB + c * 8);
        }
        __syncthreads();
        short8 af[4], bfr[4];
        for (int i = 0; i < 4; ++i)
            af[i] = *(const short8*)&lA[(wr * 64 + i * 16 + ml) * BK + qa * 8];
        for (int j = 0; j < 4; ++j)
            bfr[j] = *(const short8*)&lB[(wc * 64 + j * 16 + ml) * BK + qa * 8];
        for (int i = 0; i < 4; ++i)
            for (int j = 0; j < 4; ++j)
                acc[i][j] = __builtin_amdgcn_mfma_f32_16x16x32_bf16(af[i], bfr[j], acc[i][j], 0, 0, 0);
    }

    for (int i = 0; i < 4; ++i) {
        for (int j = 0; j < 4; ++j) {
            int col = col0 + wc * 64 + j * 16 + ml;
            float bv = bias[col];
            for (int r = 0; r < 4; ++r) {
                int row = row0 + wr * 64 + i * 16 + qa * 4 + r;
                float cv = acc[i][j][r] + bv;
                if (EPI == 0) {
                    if (col < 1024) cv *= 0.125f;
                    Cb[(size_t)row * N + col] = f2bf(cv);
                } else if (EPI == 1) {
                    cv = 0.5f * cv * (1.0f + erf_inline(cv * 0.70710678118654752f));
                    Cb[(size_t)row * N + col] = f2bf(cv);
                } else {
                    cv += res[(size_t)row * N + col];
                    Cf[(size_t)row * N + col] = cv;
                }
            }
        }
    }
}

// ---------------- transpose v slice of qkv -> vT[b,h,d,s] ----------------
__global__ __launch_bounds__(256) void transpose_v(const unsigned short* __restrict__ qkv,
                                                   unsigned short* __restrict__ vT) {
    __shared__ unsigned short tile[64][72];
    int s0 = blockIdx.x * 64;
    int pair = blockIdx.y;
    int b = pair >> 4, h = pair & 15;
    int t = threadIdx.x;
    int r = t >> 2, c0 = (t & 3) * 16;
    const unsigned short* src = qkv + (size_t)(b * S_ + s0 + r) * 3072 + 2048 + h * 64 + c0;
    *(short8*)&tile[r][c0] = *(const short8*)src;
    *(short8*)&tile[r][c0 + 8] = *(const short8*)(src + 8);
    __syncthreads();
    int d = t >> 2, sc0 = (t & 3) * 16;
    unsigned short tmp[16];
    for (int i = 0; i < 16; ++i) tmp[i] = tile[sc0 + i][d];
    unsigned short* dst = vT + ((size_t)pair * 64 + d) * S_ + s0 + sc0;
    *(short8*)dst = *(const short8*)&tmp[0];
    *(short8*)(dst + 8) = *(const short8*)&tmp[8];
}

// ---------------- flash attention v3 (R0 baseline, proven): 64 q-rows/block ----------------
// wave w owns q-rows [qc*64 + w*16, +16) and all 64 d-cols. 8 k-chunks of 128 keys.
// K chunk staged in LDS via global_load_lds with XOR source-permute swizzle:
// LDS slot s of row holds global chunk s^(row&7). Reader wants chunk qa of key
// -> slot qa^(key&7), element offset key*64 + slot*8.
// NOTE: the in-register-softmax arc (R0-R6) is closed: swapped-QK^T passed once
// (866us, spill-bound) but every pressure-relief variant failed refcheck with
// identical absmax 5.34 including a byte-exact re-run body; unexplainable from
// source. This v3 is the known-good 182.7us kernel from the 690us baseline.
__global__ __launch_bounds__(256) void attn_flash(const unsigned short* __restrict__ qkv,
                                                  const unsigned short* __restrict__ vT,
                                                  const float* __restrict__ amqf,
                                                  const float* __restrict__ negadd,
                                                  unsigned short* __restrict__ ctx) {
    __shared__ unsigned short lK[128 * 64];       // swizzled [key][slot], 16 KB
    __shared__ unsigned short lP[4][16 * 136];    // per-wave P tile, stride 136
    int qc = blockIdx.x;                          // 0..15
    int pair = blockIdx.y;
    int b = pair >> 4, h = pair & 15;
    int t = threadIdx.x, w = t >> 6, lane = t & 63;
    int qa = lane >> 4, ml = lane & 15;
    int q0 = qc * 64 + w * 16;                    // wave's first q-row

    // Q A-frags straight from global (row = q0+ml)
    const unsigned short* qrow = qkv + (size_t)(b * S_ + q0 + ml) * 3072 + h * 64;
    short8 aq0 = *(const short8*)(qrow + qa * 8);
    short8 aq1 = *(const short8*)(qrow + 32 + qa * 8);
    float amq[4];
    for (int r = 0; r < 4; ++r) amq[r] = amqf[b * S_ + q0 + qa * 4 + r];

    // staging addresses (chunk c = w*256 + i*64 + lane -> row=c>>3, slot=c&7)
    const unsigned short* ksrc[4];
    unsigned short* kdst[4];
    for (int i = 0; i < 4; ++i) {
        int c = w * 256 + i * 64 + lane;
        int row = c >> 3, slot = c & 7, e8 = slot ^ (row & 7);
        ksrc[i] = qkv + (size_t)(b * S_ + row) * 3072 + 1024 + h * 64 + e8 * 8;
        kdst[i] = lK + c * 8;
    }
    int sw0 = qa ^ (ml & 7);                // slot holding chunk qa of key (key&7 == ml&7)
    int sw1 = (qa + 4) ^ (ml & 7);          // slot holding chunk qa+4

    float m_old[4] = {-3e38f, -3e38f, -3e38f, -3e38f};
    float l[4] = {0.f, 0.f, 0.f, 0.f};
    f32x4 O[4] = {};
    unsigned short* pw = lP[w];

    for (int kc = 0; kc < 8; ++kc) {
        int kk0 = kc * 128;
        __syncthreads();                               // lK free from previous chunk
        for (int i = 0; i < 4; ++i)
            gload_lds16(ksrc[i] + (size_t)kk0 * 3072, kdst[i]);
        __syncthreads();                               // staging complete

        // scores: 8 subtiles of 16 keys
        f32x4 sacc[8];
        for (int ks = 0; ks < 8; ++ks) {
            int keyoff = (ks * 16 + ml) * 64;
            short8 bb0 = *(const short8*)(lK + keyoff + sw0 * 8);
            short8 bb1 = *(const short8*)(lK + keyoff + sw1 * 8);
            f32x4 a = {};
            a = __builtin_amdgcn_mfma_f32_16x16x32_bf16(aq0, bb0, a, 0, 0, 0);
            a = __builtin_amdgcn_mfma_f32_16x16x32_bf16(aq1, bb1, a, 0, 0, 0);
            float sb = negadd[b * S_ + kk0 + ks * 16 + ml];
            for (int r = 0; r < 4; ++r) a[r] += amq[r] + sb;
            sacc[ks] = a;
        }
        // online softmax update
        float m_new[4], alpha[4], sum[4];
        for (int r = 0; r < 4; ++r) {
            float m = m_old[r];
            for (int ks = 0; ks < 8; ++ks) m = fmaxf(m, sacc[ks][r]);
            for (int o = 8; o >= 1; o >>= 1) m = fmaxf(m, __shfl_xor(m, o, 16));
            m_new[r] = m;
            alpha[r] = __expf(m_old[r] - m);
            m_old[r] = m;
            sum[r] = 0.f;
        }
        for (int ks = 0; ks < 8; ++ks) {
            for (int r = 0; r < 4; ++r) {
                float p = __expf(sacc[ks][r] - m_new[r]);
                sum[r] += p;
                pw[(qa * 4 + r) * 136 + ks * 16 + ml] = f2bf(p);
            }
        }
        for (int r = 0; r < 4; ++r) {
            float s = sum[r];
            for (int o = 8; o >= 1; o >>= 1) s += __shfl_xor(s, o, 16);
            l[r] = l[r] * alpha[r] + s;
        }
        for (int ds = 0; ds < 4; ++ds)
            for (int r = 0; r < 4; ++r)
                O[ds][r] *= alpha[r];
        // PV: P[16x128] @ V[128x64]  (V via vT rows, contiguous in s)
        for (int ds = 0; ds < 4; ++ds) {
            const unsigned short* vtp = vT + ((size_t)pair * 64 + ds * 16 + ml) * S_ + kk0;
            for (int kst = 0; kst < 4; ++kst) {
                short8 ap = *(const short8*)(pw + ml * 136 + kst * 32 + qa * 8);
                short8 bp = *(const short8*)(vtp + kst * 32 + qa * 8);
                O[ds] = __builtin_amdgcn_mfma_f32_16x16x32_bf16(ap, bp, O[ds], 0, 0, 0);
            }
        }
    }
    // epilogue
    for (int r = 0; r < 4; ++r) {
        float inv = 1.0f / l[r];
        size_t orow = (size_t)(b * S_ + q0 + qa * 4 + r) * E_ + h * 64;
        for (int ds = 0; ds < 4; ++ds)
            ctx[orow + ds * 16 + ml] = f2bf(O[ds][r] * inv);
    }
}

// ---------------- row LayerNorm over E=1024 ----------------
template <int WRITE_BF16>
__global__ __launch_bounds__(256) void ln_kernel(const float* __restrict__ in,
                                                 const float* __restrict__ lw,
                                                 const float* __restrict__ lb,
                                                 float* __restrict__ outf,
                                                 unsigned short* __restrict__ outb) {
    int row = blockIdx.x;
    int t = threadIdx.x;
    const float* x = in + (size_t)row * E_;
    float4 v = ((const float4*)x)[t];
    float s = v.x + v.y + v.z + v.w;
    float sq = v.x * v.x + v.y * v.y + v.z * v.z + v.w * v.w;
    for (int o = 32; o >= 1; o >>= 1) {
        s += __shfl_xor(s, o, 64);
        sq += __shfl_xor(sq, o, 64);
    }
    __shared__ float red[8];
    if ((t & 63) == 0) { red[t >> 6] = s; red[4 + (t >> 6)] = sq; }
    __syncthreads();
    s = red[0] + red[1] + red[2] + red[3];
    sq = red[4] + red[5] + red[6] + red[7];
    float mu = s * (1.0f / E_);
    float var = sq * (1.0f / E_) - mu * mu;
    float rstd = rsqrtf(fmaxf(var, 0.0f) + 1e-12f);
    float4 wv = ((const float4*)lw)[t];
    float4 bv = ((const float4*)lb)[t];
    float4 o;
    o.x = (v.x - mu) * rstd * wv.x + bv.x;
    o.y = (v.y - mu) * rstd * wv.y + bv.y;
    o.z = (v.z - mu) * rstd * wv.z + bv.z;
    o.w = (v.w - mu) * rstd * wv.w + bv.w;
    ((float4*)(outf + (size_t)row * E_))[t] = o;
    if (WRITE_BF16) {
        ushort4 ob;
        ob.x = f2bf(o.x); ob.y = f2bf(o.y); ob.z = f2bf(o.z); ob.w = f2bf(o.w);
        ((ushort4*)(outb + (size_t)row * E_))[t] = ob;
    }
}

extern "C" void kernel_launch(void* const* d_in, const int* in_sizes, int n_in,
                              void* d_out, int out_size, void* d_ws, size_t ws_size,
                              hipStream_t stream) {
    const float* x        = (const float*)d_in[0];
    const int*   am       = (const int*)d_in[1];
    const int*   tt       = (const int*)d_in[2];
    const float* in_w     = (const float*)d_in[3];
    const float* in_b     = (const float*)d_in[4];
    const float* out_w    = (const float*)d_in[5];
    const float* out_b    = (const float*)d_in[6];
    const float* ln_w     = (const float*)d_in[7];
    const float* ln_b     = (const float*)d_in[8];
    const float* w_in     = (const float*)d_in[9];
    const float* b_in     = (const float*)d_in[10];
    const float* w_out    = (const float*)d_in[11];
    const float* b_out    = (const float*)d_in[12];
    float* out = (float*)d_out;

    const size_t MB = 1024 * 1024;
    char* ws = (char*)d_ws;
    unsigned short* xb    = (unsigned short*)(ws + 0);        // 16 MB (reused as hb)
    unsigned short* hb    = xb;
    unsigned short* wqkvT = (unsigned short*)(ws + 16 * MB);  // 6 MB
    unsigned short* woutT = (unsigned short*)(ws + 22 * MB);  // 2 MB
    unsigned short* winT  = (unsigned short*)(ws + 24 * MB);  // 8 MB
    unsigned short* wo2T  = (unsigned short*)(ws + 32 * MB);  // 8 MB
    unsigned short* qkvb  = (unsigned short*)(ws + 40 * MB);  // 48 MB
    unsigned short* vT    = (unsigned short*)(ws + 88 * MB);  // 16 MB
    unsigned short* ctx   = (unsigned short*)(ws + 104 * MB); // 16 MB
    float*          res1  = (float*)(ws + 120 * MB);          // 32 MB (reused for res2)
    float*          hbuf  = (float*)(ws + 152 * MB);          // 32 MB
    unsigned short* ffmid = (unsigned short*)(ws + 184 * MB); // 64 MB  -> total 248 MB
    // mask floats live in the ffmid region (unused until gemm3, attn is done by then)
    float*          amqf  = (float*)(ws + 184 * MB);          // 32 KB
    float*          negadd= (float*)(ws + 185 * MB);          // 32 KB

    // 1. cast x -> bf16; mask prep
    cast_f32_bf16<<<dim3(M_ * E_ / 1024), 256, 0, stream>>>(x, xb);
    mask_prep<<<dim3(M_ / 256), 256, 0, stream>>>(am, tt, amqf, negadd);
    // 2. transpose-cast weights
    transpose_cast<<<dim3(3 * E_ / 32, E_ / 32), 256, 0, stream>>>(in_w, wqkvT, E_, 3 * E_);
    transpose_cast<<<dim3(E_ / 32, E_ / 32), 256, 0, stream>>>(out_w, woutT, E_, E_);
    transpose_cast<<<dim3(F_ / 32, E_ / 32), 256, 0, stream>>>(w_in, winT, E_, F_);
    transpose_cast<<<dim3(E_ / 32, F_ / 32), 256, 0, stream>>>(w_out, wo2T, F_, E_);
    // 3. qkv = x @ in_proj_w + in_proj_b  (q scaled by 1/8)
    gemm_bt<0><<<dim3(3 * E_ / BN, M_ / BM), 256, 0, stream>>>(xb, wqkvT, in_b, nullptr,
                                                               qkvb, nullptr, M_, 3 * E_, E_);
    // 4. vT
    transpose_v<<<dim3(S_ / 64, B_ * H_), 256, 0, stream>>>(qkvb, vT);
    // 5. attention -> ctx
    attn_flash<<<dim3(S_ / 64, B_ * H_), 256, 0, stream>>>(qkvb, vT, amqf, negadd, ctx);
    // 6. attn_out + x  (fp32)
    gemm_bt<2><<<dim3(E_ / BN, M_ / BM), 256, 0, stream>>>(ctx, woutT, out_b, x,
                                                           nullptr, res1, M_, E_, E_);
    // 7. LN1 -> hbuf (f32) + hb (bf16)
    ln_kernel<1><<<dim3(M_), 256, 0, stream>>>(res1, ln_w, ln_b, hbuf, hb);
    // 8. ffmid = gelu(h @ w_in + b_in)
    gemm_bt<1><<<dim3(F_ / BN, M_ / BM), 256, 0, stream>>>(hb, winT, b_in, nullptr,
                                                           ffmid, nullptr, M_, F_, E_);
    // 9. ff + h (fp32)
    gemm_bt<2><<<dim3(E_ / BN, M_ / BM), 256, 0, stream>>>(ffmid, wo2T, b_out, hbuf,
                                                           nullptr, res1, M_, E_, F_);
    // 10. LN2 -> out
    ln_kernel<0><<<dim3(M_), 256, 0, stream>>>(res1, ln_w, ln_b, out, nullptr);
}

// Round 8
// 675.400 us; speedup vs baseline: 1.2824x; 1.0058x over previous
//
#include <hip/hip_runtime.h>
#include <hip/hip_bf16.h>
#include <math.h>

#define B_ 8
#define S_ 1024
#define E_ 1024
#define H_ 16
#define HD_ 64
#define F_ 4096
#define M_ (B_ * S_)   // 8192

typedef float f32x4 __attribute__((ext_vector_type(4)));
typedef short short8 __attribute__((ext_vector_type(8)));

__device__ inline unsigned short f2bf(float x) {
    union { float f; unsigned int u; } v; v.f = x;
    unsigned int r = (v.u + 0x7fffu + ((v.u >> 16) & 1u)) >> 16;
    return (unsigned short)r;
}
__device__ inline float bf2f(unsigned short u) {
    union { unsigned int u; float f; } v; v.u = ((unsigned int)u) << 16;
    return v.f;
}

// inline erf, Abramowitz-Stegun 7.1.26, |err| < 1.5e-7 — NO libcall (erff() is a
// real ABI call on this toolchain: it spilled the MFMA accumulators around 64
// calls/thread in the epilogue -> 6.8 GB of scratch traffic, 1347us dispatch)
__device__ inline float erf_inline(float x) {
    float ax = __builtin_fabsf(x);
    float t = __builtin_amdgcn_rcpf(1.0f + 0.3275911f * ax);
    float y = t * (0.254829592f + t * (-0.284496736f + t * (1.421413741f +
              t * (-1.453152027f + t * 1.061405429f))));
    float e = __expf(-ax * ax);
    float r = 1.0f - y * e;
    union { float f; unsigned int u; } s, o;
    s.f = x; o.f = r;
    o.u = (o.u & 0x7fffffffu) | (s.u & 0x80000000u);
    return o.f;
}

#define AS1 __attribute__((address_space(1)))
#define AS3 __attribute__((address_space(3)))
__device__ inline void gload_lds16(const void* g, void* l) {
    __builtin_amdgcn_global_load_lds((const AS1 unsigned int*)(g),
                                     (AS3 unsigned int*)(l), 16, 0, 0);
}

// ---------------- cast x fp32 -> bf16 ----------------
__global__ __launch_bounds__(256) void cast_f32_bf16(const float* __restrict__ in,
                                                     unsigned short* __restrict__ out) {
    int i = (blockIdx.x * 256 + threadIdx.x) * 4;
    float4 v = *(const float4*)(in + i);
    ushort4 o;
    o.x = f2bf(v.x); o.y = f2bf(v.y); o.z = f2bf(v.z); o.w = f2bf(v.w);
    *(ushort4*)(out + i) = o;
}

// ---------------- mask prep: per (b,s) additive -1e30/0 and q-side 0/1 float ----------------
__global__ __launch_bounds__(256) void mask_prep(const int* __restrict__ am,
                                                 const int* __restrict__ tt,
                                                 float* __restrict__ amqf,
                                                 float* __restrict__ negadd) {
    int i = blockIdx.x * 256 + threadIdx.x;   // i in [0, B*S)
    int s = i & (S_ - 1);
    int a = am[i], t = tt[i];
    amqf[i] = (a != 0) ? 1.0f : 0.0f;
    negadd[i] = ((t == 1) || (a == 0) || (s == 0)) ? -1e30f : 0.0f;
}

// ---------------- transpose+cast weight: in[K,N] f32 -> out[N,K] bf16 ----------------
__global__ __launch_bounds__(256) void transpose_cast(const float* __restrict__ in,
                                                      unsigned short* __restrict__ out,
                                                      int K, int N) {
    __shared__ float tile[32][33];
    int n0 = blockIdx.x * 32, k0 = blockIdx.y * 32;
    int tc = threadIdx.x & 31, tr = threadIdx.x >> 5;  // tr 0..7
    for (int i = 0; i < 4; ++i) {
        int k = k0 + tr + i * 8;
        tile[tr + i * 8][tc] = in[(size_t)k * N + n0 + tc];
    }
    __syncthreads();
    for (int i = 0; i < 4; ++i) {
        int n = n0 + tr + i * 8;
        out[(size_t)n * K + k0 + tc] = f2bf(tile[tc][tr + i * 8]);
    }
}

// ---------------- GEMM: C[M,N] = A[M,K](bf16) @ Bt[N,K]^T(bf16) + bias, epilogues ----------------
// EPI 0: qkv  -> bias, scale cols<1024 by 1/8, store bf16
// EPI 1: gelu -> bias, exact gelu (inline erf), store bf16
// EPI 2: res  -> bias + res[row*N+col], store fp32
// R6 (banked, 679us): XCD-aware bijective block swizzle (T1): all four launches
// have nwg%8==0 (1536/512/2048/512), so swz = (lin&7)*(nwg/8) + lin>>3 gives each
// XCD a contiguous chunk of the linearized grid. Pure index permutation.
#define BM 128
#define BN 128
#define BK 32
template <int EPI>
__global__ __launch_bounds__(256) void gemm_bt(const unsigned short* __restrict__ A,
                                               const unsigned short* __restrict__ Bt,
                                               const float* __restrict__ bias,
                                               const float* __restrict__ res,
                                               unsigned short* __restrict__ Cb,
                                               float* __restrict__ Cf,
                                               int M, int N, int K) {
    __shared__ unsigned short lA[BM * BK];
    __shared__ unsigned short lB[BN * BK];
    int gx = gridDim.x;
    int lin = blockIdx.x + blockIdx.y * gx;
    int nwg = gx * gridDim.y;                 // divisible by 8 for all launches
    int swz = (lin & 7) * (nwg >> 3) + (lin >> 3);
    int bx = swz % gx, by = swz / gx;
    int row0 = by * BM, col0 = bx * BN;
    int t = threadIdx.x;
    int lane = t & 63, w = t >> 6;
    int wr = w >> 1, wc = w & 1;
    int qa = lane >> 4, ml = lane & 15;

    f32x4 acc[4][4] = {};
    const unsigned short* Aptr = A + (size_t)row0 * K;
    const unsigned short* Bptr = Bt + (size_t)col0 * K;

    for (int k0 = 0; k0 < K; k0 += BK) {
        __syncthreads();
        for (int i = 0; i < 2; ++i) {
            int c = t + i * 256;
            int r = c >> 2, kc = c & 3;
            gload_lds16(Aptr + (size_t)r * K + k0 + kc * 8, lA + c * 8);
            gload_lds16(Bptr + (size_t)r * K + k0 + kc * 8, lB + c * 8);
        }
        __syncthreads();
        short8 af[4], bfr[4];
        for (int i = 0; i < 4; ++i)
            af[i] = *(const short8*)&lA[(wr * 64 + i * 16 + ml) * BK + qa * 8];
        for (int j = 0; j < 4; ++j)
            bfr[j] = *(const short8*)&lB[(wc * 64 + j * 16 + ml) * BK + qa * 8];
        for (int i = 0; i < 4; ++i)
            for (int j = 0; j < 4; ++j)
                acc[i][j] = __builtin_amdgcn_mfma_f32_16x16x32_bf16(af[i], bfr[j], acc[i][j], 0, 0, 0);
    }

    for (int i = 0; i < 4; ++i) {
        for (int j = 0; j < 4; ++j) {
            int col = col0 + wc * 64 + j * 16 + ml;
            float bv = bias[col];
            for (int r = 0; r < 4; ++r) {
                int row = row0 + wr * 64 + i * 16 + qa * 4 + r;
                float cv = acc[i][j][r] + bv;
                if (EPI == 0) {
                    if (col < 1024) cv *= 0.125f;
                    Cb[(size_t)row * N + col] = f2bf(cv);
                } else if (EPI == 1) {
                    cv = 0.5f * cv * (1.0f + erf_inline(cv * 0.70710678118654752f));
                    Cb[(size_t)row * N + col] = f2bf(cv);
                } else {
                    cv += res[(size_t)row * N + col];
                    Cf[(size_t)row * N + col] = cv;
                }
            }
        }
    }
}

// ---------------- transpose v slice of qkv -> vT[b,h,d,s] ----------------
__global__ __launch_bounds__(256) void transpose_v(const unsigned short* __restrict__ qkv,
                                                   unsigned short* __restrict__ vT) {
    __shared__ unsigned short tile[64][72];
    int s0 = blockIdx.x * 64;
    int pair = blockIdx.y;
    int b = pair >> 4, h = pair & 15;
    int t = threadIdx.x;
    int r = t >> 2, c0 = (t & 3) * 16;
    const unsigned short* src = qkv + (size_t)(b * S_ + s0 + r) * 3072 + 2048 + h * 64 + c0;
    *(short8*)&tile[r][c0] = *(const short8*)src;
    *(short8*)&tile[r][c0 + 8] = *(const short8*)(src + 8);
    __syncthreads();
    int d = t >> 2, sc0 = (t & 3) * 16;
    unsigned short tmp[16];
    for (int i = 0; i < 16; ++i) tmp[i] = tile[sc0 + i][d];
    unsigned short* dst = vT + ((size_t)pair * 64 + d) * S_ + s0 + sc0;
    *(short8*)dst = *(const short8*)&tmp[0];
    *(short8*)(dst + 8) = *(const short8*)&tmp[8];
}

// ---------------- flash attention v9: v3 body + lP aliased onto lK (LDS 33792 -> 17408) ----------------
// v3 was LDS-capped at 4 blocks/CU (Occ 45.8%) while latency-bound (MfmaUtil 7.7,
// VALU 30, HBM 11). lK (16 KB, dead after score phase) and lP (17 KB, written
// after) are temporally disjoint PER CHUNK; the only hazard is wave w writing
// lP[w] while another wave still reads lK. One extra __syncthreads between the
// score phase and the P-write phase removes it:
//   syncA (prior PV lP-reads done) -> stage lK -> syncB (loads landed) ->
//   read lK into sacc -> syncC (all lK reads retired) -> write lP -> read lP (PV)
// lP[w] is per-wave for both write and read, so no further cross-wave hazards.
// 17408 B/block -> 8 blocks/CU (wave-capped), grid = 2048 = exactly 8/CU.
// Everything else (indices, stride 136, swizzle) is the proven v3 byte-for-byte.
__global__ __launch_bounds__(256) void attn_flash(const unsigned short* __restrict__ qkv,
                                                  const unsigned short* __restrict__ vT,
                                                  const float* __restrict__ amqf,
                                                  const float* __restrict__ negadd,
                                                  unsigned short* __restrict__ ctx) {
    __shared__ unsigned short lbuf[4 * 16 * 136]; // 17408 B: lK (first 16 KB) + per-wave lP, aliased
    unsigned short* lK = lbuf;                    // swizzled [key][slot], 16 KB
    int qc = blockIdx.x;                          // 0..15
    int pair = blockIdx.y;
    int b = pair >> 4, h = pair & 15;
    int t = threadIdx.x, w = t >> 6, lane = t & 63;
    int qa = lane >> 4, ml = lane & 15;
    int q0 = qc * 64 + w * 16;                    // wave's first q-row

    // Q A-frags straight from global (row = q0+ml)
    const unsigned short* qrow = qkv + (size_t)(b * S_ + q0 + ml) * 3072 + h * 64;
    short8 aq0 = *(const short8*)(qrow + qa * 8);
    short8 aq1 = *(const short8*)(qrow + 32 + qa * 8);
    float amq[4];
    for (int r = 0; r < 4; ++r) amq[r] = amqf[b * S_ + q0 + qa * 4 + r];

    // staging addresses (chunk c = w*256 + i*64 + lane -> row=c>>3, slot=c&7)
    const unsigned short* ksrc[4];
    unsigned short* kdst[4];
    for (int i = 0; i < 4; ++i) {
        int c = w * 256 + i * 64 + lane;
        int row = c >> 3, slot = c & 7, e8 = slot ^ (row & 7);
        ksrc[i] = qkv + (size_t)(b * S_ + row) * 3072 + 1024 + h * 64 + e8 * 8;
        kdst[i] = lK + c * 8;
    }
    int sw0 = qa ^ (ml & 7);                // slot holding chunk qa of key (key&7 == ml&7)
    int sw1 = (qa + 4) ^ (ml & 7);          // slot holding chunk qa+4

    float m_old[4] = {-3e38f, -3e38f, -3e38f, -3e38f};
    float l[4] = {0.f, 0.f, 0.f, 0.f};
    f32x4 O[4] = {};
    unsigned short* pw = lbuf + w * (16 * 136);   // per-wave P tile, stride 136 (aliases lK)

    for (int kc = 0; kc < 8; ++kc) {
        int kk0 = kc * 128;
        __syncthreads();                               // A: prior PV lP-reads done; lbuf free
        for (int i = 0; i < 4; ++i)
            gload_lds16(ksrc[i] + (size_t)kk0 * 3072, kdst[i]);
        __syncthreads();                               // B: staging complete

        // scores: 8 subtiles of 16 keys
        f32x4 sacc[8];
        for (int ks = 0; ks < 8; ++ks) {
            int keyoff = (ks * 16 + ml) * 64;
            short8 bb0 = *(const short8*)(lK + keyoff + sw0 * 8);
            short8 bb1 = *(const short8*)(lK + keyoff + sw1 * 8);
            f32x4 a = {};
            a = __builtin_amdgcn_mfma_f32_16x16x32_bf16(aq0, bb0, a, 0, 0, 0);
            a = __builtin_amdgcn_mfma_f32_16x16x32_bf16(aq1, bb1, a, 0, 0, 0);
            float sb = negadd[b * S_ + kk0 + ks * 16 + ml];
            for (int r = 0; r < 4; ++r) a[r] += amq[r] + sb;
            sacc[ks] = a;
        }
        __syncthreads();                               // C: all waves done reading lK -> lP write safe

        // online softmax update
        float m_new[4], alpha[4], sum[4];
        for (int r = 0; r < 4; ++r) {
            float m = m_old[r];
            for (int ks = 0; ks < 8; ++ks) m = fmaxf(m, sacc[ks][r]);
            for (int o = 8; o >= 1; o >>= 1) m = fmaxf(m, __shfl_xor(m, o, 16));
            m_new[r] = m;
            alpha[r] = __expf(m_old[r] - m);
            m_old[r] = m;
            sum[r] = 0.f;
        }
        for (int ks = 0; ks < 8; ++ks) {
            for (int r = 0; r < 4; ++r) {
                float p = __expf(sacc[ks][r] - m_new[r]);
                sum[r] += p;
                pw[(qa * 4 + r) * 136 + ks * 16 + ml] = f2bf(p);
            }
        }
        for (int r = 0; r < 4; ++r) {
            float s = sum[r];
            for (int o = 8; o >= 1; o >>= 1) s += __shfl_xor(s, o, 16);
            l[r] = l[r] * alpha[r] + s;
        }
        for (int ds = 0; ds < 4; ++ds)
            for (int r = 0; r < 4; ++r)
                O[ds][r] *= alpha[r];
        // PV: P[16x128] @ V[128x64]  (V via vT rows, contiguous in s)
        for (int ds = 0; ds < 4; ++ds) {
            const unsigned short* vtp = vT + ((size_t)pair * 64 + ds * 16 + ml) * S_ + kk0;
            for (int kst = 0; kst < 4; ++kst) {
                short8 ap = *(const short8*)(pw + ml * 136 + kst * 32 + qa * 8);
                short8 bp = *(const short8*)(vtp + kst * 32 + qa * 8);
                O[ds] = __builtin_amdgcn_mfma_f32_16x16x32_bf16(ap, bp, O[ds], 0, 0, 0);
            }
        }
    }
    // epilogue
    for (int r = 0; r < 4; ++r) {
        float inv = 1.0f / l[r];
        size_t orow = (size_t)(b * S_ + q0 + qa * 4 + r) * E_ + h * 64;
        for (int ds = 0; ds < 4; ++ds)
            ctx[orow + ds * 16 + ml] = f2bf(O[ds][r] * inv);
    }
}

// ---------------- row LayerNorm over E=1024 ----------------
template <int WRITE_BF16>
__global__ __launch_bounds__(256) void ln_kernel(const float* __restrict__ in,
                                                 const float* __restrict__ lw,
                                                 const float* __restrict__ lb,
                                                 float* __restrict__ outf,
                                                 unsigned short* __restrict__ outb) {
    int row = blockIdx.x;
    int t = threadIdx.x;
    const float* x = in + (size_t)row * E_;
    float4 v = ((const float4*)x)[t];
    float s = v.x + v.y + v.z + v.w;
    float sq = v.x * v.x + v.y * v.y + v.z * v.z + v.w * v.w;
    for (int o = 32; o >= 1; o >>= 1) {
        s += __shfl_xor(s, o, 64);
        sq += __shfl_xor(sq, o, 64);
    }
    __shared__ float red[8];
    if ((t & 63) == 0) { red[t >> 6] = s; red[4 + (t >> 6)] = sq; }
    __syncthreads();
    s = red[0] + red[1] + red[2] + red[3];
    sq = red[4] + red[5] + red[6] + red[7];
    float mu = s * (1.0f / E_);
    float var = sq * (1.0f / E_) - mu * mu;
    float rstd = rsqrtf(fmaxf(var, 0.0f) + 1e-12f);
    float4 wv = ((const float4*)lw)[t];
    float4 bv = ((const float4*)lb)[t];
    float4 o;
    o.x = (v.x - mu) * rstd * wv.x + bv.x;
    o.y = (v.y - mu) * rstd * wv.y + bv.y;
    o.z = (v.z - mu) * rstd * wv.z + bv.z;
    o.w = (v.w - mu) * rstd * wv.w + bv.w;
    ((float4*)(outf + (size_t)row * E_))[t] = o;
    if (WRITE_BF16) {
        ushort4 ob;
        ob.x = f2bf(o.x); ob.y = f2bf(o.y); ob.z = f2bf(o.z); ob.w = f2bf(o.w);
        ((ushort4*)(outb + (size_t)row * E_))[t] = ob;
    }
}

extern "C" void kernel_launch(void* const* d_in, const int* in_sizes, int n_in,
                              void* d_out, int out_size, void* d_ws, size_t ws_size,
                              hipStream_t stream) {
    const float* x        = (const float*)d_in[0];
    const int*   am       = (const int*)d_in[1];
    const int*   tt       = (const int*)d_in[2];
    const float* in_w     = (const float*)d_in[3];
    const float* in_b     = (const float*)d_in[4];
    const float* out_w    = (const float*)d_in[5];
    const float* out_b    = (const float*)d_in[6];
    const float* ln_w     = (const float*)d_in[7];
    const float* ln_b     = (const float*)d_in[8];
    const float* w_in     = (const float*)d_in[9];
    const float* b_in     = (const float*)d_in[10];
    const float* w_out    = (const float*)d_in[11];
    const float* b_out    = (const float*)d_in[12];
    float* out = (float*)d_out;

    const size_t MB = 1024 * 1024;
    char* ws = (char*)d_ws;
    unsigned short* xb    = (unsigned short*)(ws + 0);        // 16 MB (reused as hb)
    unsigned short* hb    = xb;
    unsigned short* wqkvT = (unsigned short*)(ws + 16 * MB);  // 6 MB
    unsigned short* woutT = (unsigned short*)(ws + 22 * MB);  // 2 MB
    unsigned short* winT  = (unsigned short*)(ws + 24 * MB);  // 8 MB
    unsigned short* wo2T  = (unsigned short*)(ws + 32 * MB);  // 8 MB
    unsigned short* qkvb  = (unsigned short*)(ws + 40 * MB);  // 48 MB
    unsigned short* vT    = (unsigned short*)(ws + 88 * MB);  // 16 MB
    unsigned short* ctx   = (unsigned short*)(ws + 104 * MB); // 16 MB
    float*          res1  = (float*)(ws + 120 * MB);          // 32 MB (reused for res2)
    float*          hbuf  = (float*)(ws + 152 * MB);          // 32 MB
    unsigned short* ffmid = (unsigned short*)(ws + 184 * MB); // 64 MB  -> total 248 MB
    // mask floats live in the ffmid region (unused until gemm3, attn is done by then)
    float*          amqf  = (float*)(ws + 184 * MB);          // 32 KB
    float*          negadd= (float*)(ws + 185 * MB);          // 32 KB

    // 1. cast x -> bf16; mask prep
    cast_f32_bf16<<<dim3(M_ * E_ / 1024), 256, 0, stream>>>(x, xb);
    mask_prep<<<dim3(M_ / 256), 256, 0, stream>>>(am, tt, amqf, negadd);
    // 2. transpose-cast weights
    transpose_cast<<<dim3(3 * E_ / 32, E_ / 32), 256, 0, stream>>>(in_w, wqkvT, E_, 3 * E_);
    transpose_cast<<<dim3(E_ / 32, E_ / 32), 256, 0, stream>>>(out_w, woutT, E_, E_);
    transpose_cast<<<dim3(F_ / 32, E_ / 32), 256, 0, stream>>>(w_in, winT, E_, F_);
    transpose_cast<<<dim3(E_ / 32, F_ / 32), 256, 0, stream>>>(w_out, wo2T, F_, E_);
    // 3. qkv = x @ in_proj_w + in_proj_b  (q scaled by 1/8)
    gemm_bt<0><<<dim3(3 * E_ / BN, M_ / BM), 256, 0, stream>>>(xb, wqkvT, in_b, nullptr,
                                                               qkvb, nullptr, M_, 3 * E_, E_);
    // 4. vT
    transpose_v<<<dim3(S_ / 64, B_ * H_), 256, 0, stream>>>(qkvb, vT);
    // 5. attention -> ctx
    attn_flash<<<dim3(S_ / 64, B_ * H_), 256, 0, stream>>>(qkvb, vT, amqf, negadd, ctx);
    // 6. attn_out + x  (fp32)
    gemm_bt<2><<<dim3(E_ / BN, M_ / BM), 256, 0, stream>>>(ctx, woutT, out_b, x,
                                                           nullptr, res1, M_, E_, E_);
    // 7. LN1 -> hbuf (f32) + hb (bf16)
    ln_kernel<1><<<dim3(M_), 256, 0, stream>>>(res1, ln_w, ln_b, hbuf, hb);
    // 8. ffmid = gelu(h @ w_in + b_in)
    gemm_bt<1><<<dim3(F_ / BN, M_ / BM), 256, 0, stream>>>(hb, winT, b_in, nullptr,
                                                           ffmid, nullptr, M_, F_, E_);
    // 9. ff + h (fp32)
    gemm_bt<2><<<dim3(E_ / BN, M_ / BM), 256, 0, stream>>>(ffmid, wo2T, b_out, hbuf,
                                                           nullptr, res1, M_, E_, F_);
    // 10. LN2 -> out
    ln_kernel<0><<<dim3(M_), 256, 0, stream>>>(res1, ln_w, ln_b, out, nullptr);
}